// Round 3
// baseline (431.191 us; speedup 1.0000x reference)
//
#include <hip/hip_runtime.h>
#include <math.h>

#define N_NODES 200000
#define NGRAPH  512
#define HID     256

typedef __attribute__((ext_vector_type(8))) short s16x8;
typedef __attribute__((ext_vector_type(4))) float f32x4;

// ---------------------------------------------------------------------------
// Kernel 1: gate g[i] = relu(x @ w1 + b1) @ w2 + b2, x fp32.
// fp32 -> bf16 hi/lo split, 3x MFMA 16x16x32 (hh + lh + hl); epilogue fp32.
// One wave per 16-node tile, grid-stride.
// ---------------------------------------------------------------------------
__global__ __launch_bounds__(256) void gate_mfma(
    const float* __restrict__ x,
    const float* __restrict__ w1,
    const float* __restrict__ b1,
    const float* __restrict__ w2,
    const float* __restrict__ b2,
    float* __restrict__ g)
{
  // w1 transposed [n][k] as bf16 hi/lo. Row pitch 264 shorts (16B-aligned rows).
  __shared__ __align__(16) short w1h[64 * 264];
  __shared__ __align__(16) short w1l[64 * 264];
  const int tid = threadIdx.x;
  for (int i = tid; i < 256 * 64; i += 256) {   // i = k*64 + n
    int k = i >> 6, n = i & 63;
    float f = w1[i];
    unsigned int u = __float_as_uint(f);
    float hf = __uint_as_float(u & 0xffff0000u);
    float lf = f - hf;                           // exact residual
    w1h[n * 264 + k] = (short)(u >> 16);
    w1l[n * 264 + k] = (short)(__float_as_uint(lf) >> 16);
  }
  __syncthreads();

  const int lane = tid & 63;
  const int q = lane >> 4;   // k-quad
  const int c = lane & 15;   // m (A rows) / n (B cols) / col (C/D)

  float b1v[4], w2v[4];
#pragma unroll
  for (int nt = 0; nt < 4; ++nt) {
    b1v[nt] = b1[nt * 16 + c];
    w2v[nt] = w2[nt * 16 + c];
  }
  const float b2v = b2[0];

  const int wave = blockIdx.x * 4 + (tid >> 6);
  const int nwaves = gridDim.x * 4;
  for (int tile = wave; tile < N_NODES / 16; tile += nwaves) {
    const int n0 = tile * 16;
    const float* xrow = x + (size_t)(n0 + c) * HID + q * 8;  // A[m=c][k=kt*32+q*8+j]

    s16x8 ah[8], al[8];
#pragma unroll
    for (int kt = 0; kt < 8; ++kt) {
      float4 f0 = *(const float4*)(xrow + kt * 32);
      float4 f1 = *(const float4*)(xrow + kt * 32 + 4);
      float fv[8] = {f0.x, f0.y, f0.z, f0.w, f1.x, f1.y, f1.z, f1.w};
      s16x8 h, l;
#pragma unroll
      for (int j = 0; j < 8; ++j) {
        unsigned int u = __float_as_uint(fv[j]);
        h[j] = (short)(u >> 16);
        float hf = __uint_as_float(u & 0xffff0000u);
        float lf = fv[j] - hf;
        l[j] = (short)(__float_as_uint(lf) >> 16);
      }
      ah[kt] = h; al[kt] = l;
    }

    f32x4 acc[4];
#pragma unroll
    for (int nt = 0; nt < 4; ++nt) acc[nt] = (f32x4){0.f, 0.f, 0.f, 0.f};

#pragma unroll
    for (int kt = 0; kt < 8; ++kt) {
#pragma unroll
      for (int nt = 0; nt < 4; ++nt) {
        const int off = (nt * 16 + c) * 264 + kt * 32 + q * 8;
        s16x8 bh = *(const s16x8*)&w1h[off];
        s16x8 bl = *(const s16x8*)&w1l[off];
        acc[nt] = __builtin_amdgcn_mfma_f32_16x16x32_bf16(ah[kt], bh, acc[nt], 0, 0, 0);
        acc[nt] = __builtin_amdgcn_mfma_f32_16x16x32_bf16(al[kt], bh, acc[nt], 0, 0, 0);
        acc[nt] = __builtin_amdgcn_mfma_f32_16x16x32_bf16(ah[kt], bl, acc[nt], 0, 0, 0);
      }
    }

    // D[row=4q+r][col=nt*16+c]; h=relu(D+b1); g = sum_cols h*w2 + b2
#pragma unroll
    for (int r = 0; r < 4; ++r) {
      float sv = 0.f;
#pragma unroll
      for (int nt = 0; nt < 4; ++nt) {
        float h = acc[nt][r] + b1v[nt];
        h = h > 0.f ? h : 0.f;
        sv += h * w2v[nt];
      }
      sv += __shfl_xor(sv, 1, 64);
      sv += __shfl_xor(sv, 2, 64);
      sv += __shfl_xor(sv, 4, 64);
      sv += __shfl_xor(sv, 8, 64);
      if (c == 0) g[n0 + q * 4 + r] = sv + b2v;
    }
  }
}

// ---------------------------------------------------------------------------
// Kernel 2: per-segment fused pooling (batch sorted -> contiguous slice).
// Block = segment. Computes g_max, then streams x once: mean/max/attn.
// ---------------------------------------------------------------------------
__global__ __launch_bounds__(256) void pool_seg(
    const float* __restrict__ x,
    const float* __restrict__ g,
    const int* __restrict__ batch,
    float* __restrict__ zbuf)
{
  const int seg = blockIdx.x;
  const int tid = threadIdx.x;
  const int q = tid >> 6;     // wave id: nodes i0+q, i0+4+q, ...
  const int lane = tid & 63;  // owns features lane*4 .. lane*4+3

  __shared__ int sbounds[2];
  __shared__ float sred[256];
  __shared__ float part[4 * 3 * 256];
  __shared__ float dpart[4];

  if (tid < 2) {  // lower_bound(batch, seg) / lower_bound(batch, seg+1)
    int target = seg + tid;
    int lo = 0, hi = N_NODES;
    while (lo < hi) { int mid = (lo + hi) >> 1; if (batch[mid] < target) lo = mid + 1; else hi = mid; }
    sbounds[tid] = lo;
  }
  __syncthreads();
  const int s = sbounds[0], e = sbounds[1];
  const int cnt = e - s;

  // phase 1: segment g_max
  float gm = -INFINITY;
  for (int i = s + tid; i < e; i += 256) gm = fmaxf(gm, g[i]);
  sred[tid] = gm;
  __syncthreads();
  for (int w = 128; w > 0; w >>= 1) {
    if (tid < w) sred[tid] = fmaxf(sred[tid], sred[tid + w]);
    __syncthreads();
  }
  const float gmax = (cnt > 0) ? sred[0] : 0.f;

  // phase 2: stream x slice
  f32x4 sum = (f32x4){0.f, 0.f, 0.f, 0.f};
  f32x4 mx  = (f32x4){-INFINITY, -INFINITY, -INFINITY, -INFINITY};
  f32x4 at  = (f32x4){0.f, 0.f, 0.f, 0.f};
  float den = 0.f;

  const int mainEnd = s + (cnt & ~15);
  for (int i0 = s; i0 < mainEnd; i0 += 16) {
    float4 v[4]; float gi[4];
#pragma unroll
    for (int u = 0; u < 4; ++u) {
      int idx = i0 + u * 4 + q;
      v[u] = *(const float4*)(x + (size_t)idx * HID + lane * 4);
      gi[u] = g[idx];
    }
#pragma unroll
    for (int u = 0; u < 4; ++u) {
      float ei = __expf(fminf(gi[u] - gmax, 0.f));
      den += ei;
      f32x4 f = (f32x4){v[u].x, v[u].y, v[u].z, v[u].w};
      sum = sum + f;
      mx[0] = fmaxf(mx[0], f[0]); mx[1] = fmaxf(mx[1], f[1]);
      mx[2] = fmaxf(mx[2], f[2]); mx[3] = fmaxf(mx[3], f[3]);
      at[0] = fmaf(ei, f[0], at[0]); at[1] = fmaf(ei, f[1], at[1]);
      at[2] = fmaf(ei, f[2], at[2]); at[3] = fmaf(ei, f[3], at[3]);
    }
  }
  for (int idx = mainEnd + q; idx < e; idx += 4) {  // tail (<16 nodes)
    float4 v = *(const float4*)(x + (size_t)idx * HID + lane * 4);
    float ei = __expf(fminf(g[idx] - gmax, 0.f));
    den += ei;
    f32x4 f = (f32x4){v.x, v.y, v.z, v.w};
    sum = sum + f;
    mx[0] = fmaxf(mx[0], f[0]); mx[1] = fmaxf(mx[1], f[1]);
    mx[2] = fmaxf(mx[2], f[2]); mx[3] = fmaxf(mx[3], f[3]);
    at[0] = fmaf(ei, f[0], at[0]); at[1] = fmaf(ei, f[1], at[1]);
    at[2] = fmaf(ei, f[2], at[2]); at[3] = fmaf(ei, f[3], at[3]);
  }

  // combine the 4 waves
  {
    int f = lane * 4;
    float* p0 = &part[(q * 3 + 0) * 256];
    float* p1 = &part[(q * 3 + 1) * 256];
    float* p2 = &part[(q * 3 + 2) * 256];
#pragma unroll
    for (int j = 0; j < 4; ++j) { p0[f + j] = sum[j]; p1[f + j] = mx[j]; p2[f + j] = at[j]; }
  }
  if (lane == 0) dpart[q] = den;
  __syncthreads();
  {
    int f = tid;
    float S = 0.f, M = -INFINITY, A = 0.f;
#pragma unroll
    for (int qq = 0; qq < 4; ++qq) {
      S += part[(qq * 3 + 0) * 256 + f];
      M = fmaxf(M, part[(qq * 3 + 1) * 256 + f]);
      A += part[(qq * 3 + 2) * 256 + f];
    }
    float D = dpart[0] + dpart[1] + dpart[2] + dpart[3];
    float* zr = zbuf + (size_t)seg * 768;
    zr[f]       = (cnt > 0) ? S / (float)cnt : 0.f;
    zr[256 + f] = (cnt > 0) ? M : 0.f;
    zr[512 + f] = (cnt > 0) ? A / fmaxf(D, 1e-16f) : 0.f;
  }
}

// ---------------------------------------------------------------------------
// Kernel 3: y = z @ wp + bp, LayerNorm (two-pass), fp32 out. 2 graphs/block.
// ---------------------------------------------------------------------------
__global__ __launch_bounds__(256) void head_ln(
    const float* __restrict__ zbuf,
    const float* __restrict__ wp,
    const float* __restrict__ bp,
    const float* __restrict__ gam,
    const float* __restrict__ bet,
    float* __restrict__ out)
{
  const int g0 = blockIdx.x * 2;
  const int t = threadIdx.x;
  __shared__ float z0[768], z1[768];
  __shared__ f32x4 red[256];
  for (int i = t; i < 768; i += 256) {
    z0[i] = zbuf[(size_t)g0 * 768 + i];
    z1[i] = zbuf[(size_t)(g0 + 1) * 768 + i];
  }
  __syncthreads();

  float a0 = bp[t];
  float a1 = a0;
#pragma unroll 8
  for (int k = 0; k < 768; ++k) {
    float wv = wp[k * 256 + t];
    a0 = fmaf(z0[k], wv, a0);
    a1 = fmaf(z1[k], wv, a1);
  }

  // pass 1: means
  red[t] = (f32x4){a0, a1, 0.f, 0.f};
  __syncthreads();
  for (int w = 128; w > 0; w >>= 1) {
    if (t < w) red[t] = red[t] + red[t + w];
    __syncthreads();
  }
  const float inv = 1.f / 256.f;
  float mu0 = red[0].x * inv, mu1 = red[0].y * inv;
  __syncthreads();
  // pass 2: variance
  float d0 = a0 - mu0, d1 = a1 - mu1;
  red[t] = (f32x4){d0 * d0, d1 * d1, 0.f, 0.f};
  __syncthreads();
  for (int w = 128; w > 0; w >>= 1) {
    if (t < w) red[t] = red[t] + red[t + w];
    __syncthreads();
  }
  float v0 = red[0].x * inv, v1 = red[0].y * inv;
  float is0 = rsqrtf(v0 + 1e-5f);
  float is1 = rsqrtf(v1 + 1e-5f);
  float gv = gam[t], bv = bet[t];
  out[(size_t)g0 * 256 + t]       = fmaf(d0 * is0, gv, bv);
  out[(size_t)(g0 + 1) * 256 + t] = fmaf(d1 * is1, gv, bv);
}

// ---------------------------------------------------------------------------
extern "C" void kernel_launch(void* const* d_in, const int* in_sizes, int n_in,
                              void* d_out, int out_size, void* d_ws, size_t ws_size,
                              hipStream_t stream) {
  const float* x   = (const float*)d_in[0];
  const int*   bat = (const int*)d_in[1];
  const float* w1  = (const float*)d_in[2];
  const float* b1  = (const float*)d_in[3];
  const float* w2  = (const float*)d_in[4];
  const float* b2  = (const float*)d_in[5];
  const float* wp  = (const float*)d_in[6];
  const float* bp  = (const float*)d_in[7];
  const float* gam = (const float*)d_in[8];
  const float* bet = (const float*)d_in[9];
  float* out = (float*)d_out;

  // ws layout: g (200000 f32 @ 0), zbuf (512*768 f32 @ 800000)
  float* g    = (float*)d_ws;
  float* zbuf = (float*)((char*)d_ws + 800000);

  hipLaunchKernelGGL(gate_mfma, dim3(1024), dim3(256), 0, stream, x, w1, b1, w2, b2, g);
  hipLaunchKernelGGL(pool_seg,  dim3(NGRAPH), dim3(256), 0, stream, x, g, bat, zbuf);
  hipLaunchKernelGGL(head_ln,   dim3(NGRAPH / 2), dim3(256), 0, stream, zbuf, wp, bp, gam, bet, out);
}

// Round 4
// 390.276 us; speedup vs baseline: 1.1048x; 1.1048x over previous
//
#include <hip/hip_runtime.h>
#include <math.h>

#define N_NODES 200000
#define NGRAPH  512
#define HID     256

typedef __attribute__((ext_vector_type(8))) short s16x8;
typedef __attribute__((ext_vector_type(4))) float f32x4;

__device__ __forceinline__ unsigned short f2bf_rne(float f) {
  unsigned int u = __float_as_uint(f);
  return (unsigned short)((u + 0x7fffu + ((u >> 16) & 1u)) >> 16);
}

// ---------------------------------------------------------------------------
// Fused gate + pooling, ONE pass over x (online softmax).
// Block = one segment (batch sorted -> contiguous slice). 4 waves.
// Per 64-node chunk: async-stage fp32 rows to LDS; wave w computes the gate
// for nodes w*16..w*16+15 via bf16 MFMA (A = x RNE-bf16, B = w1 RNE-bf16 in
// VGPRs), broadcasts g by shuffles, then updates running mean/max/attn with
// online-softmax rescaling. Merge the 4 waves' states at the end.
// ---------------------------------------------------------------------------
__global__ __launch_bounds__(256, 2) void fused_gate_pool(
    const float* __restrict__ x,
    const int* __restrict__ batch,
    const float* __restrict__ w1,
    const float* __restrict__ b1,
    const float* __restrict__ w2,
    const float* __restrict__ b2,
    float* __restrict__ zbuf)
{
  __shared__ __align__(16) float chunk_f[64 * 256];  // 64 KB: w1 staging, then x chunks, then merge scratch
  __shared__ int sbounds[2];
  __shared__ float sm[4], sd[4];

  const int tid = threadIdx.x;
  const int w = tid >> 6;      // wave id: owns nodes w*16 .. w*16+15 of each chunk
  const int lane = tid & 63;
  const int q = lane >> 4;     // k-quad
  const int c = lane & 15;     // A row (m) / B col (n) / D col

  // --- segment bounds ---
  if (tid < 2) {
    int target = blockIdx.x + tid;
    int lo = 0, hi = N_NODES;
    while (lo < hi) { int mid = (lo + hi) >> 1; if (batch[mid] < target) lo = mid + 1; else hi = mid; }
    sbounds[tid] = lo;
  }

  // --- stage w1 (fp32, exactly 64 KB) into chunk_f; extract B fragments ---
  {
    const float4* src = (const float4*)w1;
    float4* dst = (float4*)chunk_f;
    for (int i = tid; i < 4096; i += 256) dst[i] = src[i];
  }
  __syncthreads();
  s16x8 bh[8][4];   // B[k = kt*32 + q*8 + j][n = nt*16 + c], RNE bf16 — 128 VGPRs
#pragma unroll
  for (int kt = 0; kt < 8; ++kt)
#pragma unroll
    for (int nt = 0; nt < 4; ++nt) {
      s16x8 v;
#pragma unroll
      for (int j = 0; j < 8; ++j)
        v[j] = (short)f2bf_rne(chunk_f[(kt * 32 + q * 8 + j) * 64 + nt * 16 + c]);
      bh[kt][nt] = v;
    }
  float b1v[4], w2v[4];
#pragma unroll
  for (int nt = 0; nt < 4; ++nt) { b1v[nt] = b1[nt * 16 + c]; w2v[nt] = w2[nt * 16 + c]; }
  const float b2v = b2[0];
  const int s = sbounds[0], e = sbounds[1];
  const int cnt = e - s;
  __syncthreads();   // w1 staging done; chunk_f free for x chunks

  // --- per-wave online state ---
  f32x4 sum = (f32x4){0.f, 0.f, 0.f, 0.f};
  f32x4 mx  = (f32x4){-INFINITY, -INFINITY, -INFINITY, -INFINITY};
  f32x4 at  = (f32x4){0.f, 0.f, 0.f, 0.f};
  float den = 0.f, m = -INFINITY;

  const int nchunks = (cnt + 63) >> 6;
  for (int ch = 0; ch < nchunks; ++ch) {
    const int base = s + (ch << 6);
    const int nvalid = min(64, e - base);

    // async stage: wave w stages rows {it*4 + w} (1 KB per inst, lane*16B)
#pragma unroll
    for (int it = 0; it < 16; ++it) {
      int row = it * 4 + w;
      if (row < nvalid) {
        const float* gsrc = x + (size_t)(base + row) * HID + lane * 4;
        float* ldst = &chunk_f[row * 256 + lane * 4];
        __builtin_amdgcn_global_load_lds(
            (const __attribute__((address_space(1))) unsigned int*)gsrc,
            (__attribute__((address_space(3))) unsigned int*)ldst, 16, 0, 0);
      }
    }
    __syncthreads();  // staged chunk visible (compiler drains vmcnt before barrier)

    const int lim = min(16, nvalid - w * 16);  // wave-uniform
    if (lim > 0) {
      // gate MFMA: A row = w*16 + c, k = kt*32 + q*8 + j
      f32x4 acc[4];
#pragma unroll
      for (int nt = 0; nt < 4; ++nt) acc[nt] = (f32x4){0.f, 0.f, 0.f, 0.f};
#pragma unroll
      for (int kt = 0; kt < 8; ++kt) {
        const float* ar = &chunk_f[(w * 16 + c) * 256 + kt * 32 + q * 8];
        float4 f0 = *(const float4*)ar;
        float4 f1 = *(const float4*)(ar + 4);
        s16x8 ah;
        ah[0] = (short)f2bf_rne(f0.x); ah[1] = (short)f2bf_rne(f0.y);
        ah[2] = (short)f2bf_rne(f0.z); ah[3] = (short)f2bf_rne(f0.w);
        ah[4] = (short)f2bf_rne(f1.x); ah[5] = (short)f2bf_rne(f1.y);
        ah[6] = (short)f2bf_rne(f1.z); ah[7] = (short)f2bf_rne(f1.w);
#pragma unroll
        for (int nt = 0; nt < 4; ++nt)
          acc[nt] = __builtin_amdgcn_mfma_f32_16x16x32_bf16(ah, bh[kt][nt], acc[nt], 0, 0, 0);
      }

      // epilogue: D[row=4q+r][col=nt*16+c]; butterfly over c gives every lane
      // of quad q the gate value of local row 4q+r.
      float gr[4];
#pragma unroll
      for (int r = 0; r < 4; ++r) {
        float sv = 0.f;
#pragma unroll
        for (int nt = 0; nt < 4; ++nt) {
          float h = acc[nt][r] + b1v[nt];
          h = h > 0.f ? h : 0.f;
          sv += h * w2v[nt];
        }
        sv += __shfl_xor(sv, 1, 64);
        sv += __shfl_xor(sv, 2, 64);
        sv += __shfl_xor(sv, 4, 64);
        sv += __shfl_xor(sv, 8, 64);
        gr[r] = sv + b2v;
      }

      // chunk max over valid rows
      float gm = -INFINITY;
#pragma unroll
      for (int i = 0; i < 16; ++i) {
        float gv = __shfl(gr[i & 3], (i >> 2) << 4, 64);
        if (i < lim) gm = fmaxf(gm, gv);
      }
      float m_new = fmaxf(m, gm);
      float alpha = (m == -INFINITY) ? 0.f : __expf(m - m_new);
      at = at * alpha;
      den *= alpha;
      m = m_new;

      // pool update: read rows back from LDS (conflict-free b128)
      for (int i = 0; i < lim; ++i) {
        float gv = __shfl(gr[i & 3], (i >> 2) << 4, 64);
        float ei = __expf(gv - m_new);
        den += ei;
        float4 v = *(const float4*)&chunk_f[(w * 16 + i) * 256 + lane * 4];
        f32x4 f = (f32x4){v.x, v.y, v.z, v.w};
        sum = sum + f;
        mx[0] = fmaxf(mx[0], f[0]); mx[1] = fmaxf(mx[1], f[1]);
        mx[2] = fmaxf(mx[2], f[2]); mx[3] = fmaxf(mx[3], f[3]);
        at[0] = fmaf(ei, f[0], at[0]); at[1] = fmaf(ei, f[1], at[1]);
        at[2] = fmaf(ei, f[2], at[2]); at[3] = fmaf(ei, f[3], at[3]);
      }
    }
    __syncthreads();  // all waves done reading chunk_f; safe to restage
  }

  // --- merge the 4 waves (reuse chunk_f as scratch) ---
  {
    float* p0 = &chunk_f[(w * 3 + 0) * 256];
    float* p1 = &chunk_f[(w * 3 + 1) * 256];
    float* p2 = &chunk_f[(w * 3 + 2) * 256];
    int f = lane * 4;
#pragma unroll
    for (int j = 0; j < 4; ++j) { p0[f + j] = sum[j]; p1[f + j] = mx[j]; p2[f + j] = at[j]; }
    if (lane == 0) { sm[w] = m; sd[w] = den; }
  }
  __syncthreads();
  {
    int f = tid;
    float M = fmaxf(fmaxf(sm[0], sm[1]), fmaxf(sm[2], sm[3]));
    float S = 0.f, MX = -INFINITY, A = 0.f, D = 0.f;
#pragma unroll
    for (int ww = 0; ww < 4; ++ww) {
      float sc = (sm[ww] == -INFINITY) ? 0.f : __expf(sm[ww] - M);
      S += chunk_f[(ww * 3 + 0) * 256 + f];
      MX = fmaxf(MX, chunk_f[(ww * 3 + 1) * 256 + f]);
      A = fmaf(sc, chunk_f[(ww * 3 + 2) * 256 + f], A);
      D = fmaf(sc, sd[ww], D);
    }
    float* zr = zbuf + (size_t)blockIdx.x * 768;
    zr[f]       = (cnt > 0) ? S / (float)cnt : 0.f;
    zr[256 + f] = (cnt > 0) ? MX : 0.f;
    zr[512 + f] = (cnt > 0) ? A / fmaxf(D, 1e-16f) : 0.f;
  }
}

// ---------------------------------------------------------------------------
// Kernel 2: y = z @ wp + bp, LayerNorm (two-pass), fp32 out. 2 graphs/block.
// ---------------------------------------------------------------------------
__global__ __launch_bounds__(256) void head_ln(
    const float* __restrict__ zbuf,
    const float* __restrict__ wp,
    const float* __restrict__ bp,
    const float* __restrict__ gam,
    const float* __restrict__ bet,
    float* __restrict__ out)
{
  const int g0 = blockIdx.x * 2;
  const int t = threadIdx.x;
  __shared__ float z0[768], z1[768];
  __shared__ f32x4 red[256];
  for (int i = t; i < 768; i += 256) {
    z0[i] = zbuf[(size_t)g0 * 768 + i];
    z1[i] = zbuf[(size_t)(g0 + 1) * 768 + i];
  }
  __syncthreads();

  float a0 = bp[t];
  float a1 = a0;
#pragma unroll 8
  for (int k = 0; k < 768; ++k) {
    float wv = wp[k * 256 + t];
    a0 = fmaf(z0[k], wv, a0);
    a1 = fmaf(z1[k], wv, a1);
  }

  red[t] = (f32x4){a0, a1, 0.f, 0.f};
  __syncthreads();
  for (int wd = 128; wd > 0; wd >>= 1) {
    if (t < wd) red[t] = red[t] + red[t + wd];
    __syncthreads();
  }
  const float inv = 1.f / 256.f;
  float mu0 = red[0].x * inv, mu1 = red[0].y * inv;
  __syncthreads();
  float d0 = a0 - mu0, d1 = a1 - mu1;
  red[t] = (f32x4){d0 * d0, d1 * d1, 0.f, 0.f};
  __syncthreads();
  for (int wd = 128; wd > 0; wd >>= 1) {
    if (t < wd) red[t] = red[t] + red[t + wd];
    __syncthreads();
  }
  float v0 = red[0].x * inv, v1 = red[0].y * inv;
  float is0 = rsqrtf(v0 + 1e-5f);
  float is1 = rsqrtf(v1 + 1e-5f);
  float gv = gam[t], bv = bet[t];
  out[(size_t)g0 * 256 + t]       = fmaf(d0 * is0, gv, bv);
  out[(size_t)(g0 + 1) * 256 + t] = fmaf(d1 * is1, gv, bv);
}

// ---------------------------------------------------------------------------
extern "C" void kernel_launch(void* const* d_in, const int* in_sizes, int n_in,
                              void* d_out, int out_size, void* d_ws, size_t ws_size,
                              hipStream_t stream) {
  const float* x   = (const float*)d_in[0];
  const int*   bat = (const int*)d_in[1];
  const float* w1  = (const float*)d_in[2];
  const float* b1  = (const float*)d_in[3];
  const float* w2  = (const float*)d_in[4];
  const float* b2  = (const float*)d_in[5];
  const float* wp  = (const float*)d_in[6];
  const float* bp  = (const float*)d_in[7];
  const float* gam = (const float*)d_in[8];
  const float* bet = (const float*)d_in[9];
  float* out = (float*)d_out;

  float* zbuf = (float*)d_ws;  // 512*768 fp32

  hipLaunchKernelGGL(fused_gate_pool, dim3(NGRAPH), dim3(256), 0, stream,
                     x, bat, w1, b1, w2, b2, zbuf);
  hipLaunchKernelGGL(head_ln, dim3(NGRAPH / 2), dim3(256), 0, stream,
                     zbuf, wp, bp, gam, bet, out);
}